// Round 3
// baseline (223.002 us; speedup 1.0000x reference)
//
#include <hip/hip_runtime.h>

// Problem constants (fixed by the reference): n=8, c=16, H=W=512.
#define NIMG 8
#define NCLS 16
#define HW      262144         // 512*512 = 2^18 pixels per image
#define PXB     2048           // pixels per block (contiguous strip)
#define NBLK    1024           // (NIMG*HW)/PXB ; 128 blocks per image
#define GROUPS  2              // float4 pixel-groups per thread (8 px/thread)

// ---------------------------------------------------------------------------
// Main pass — channel-streamed online log-softmax.
// Block b owns pixels [b*2048, (b+1)*2048) of one image. For each channel c
// (outer loop) the block reads ONE contiguous 8-KB strip of pred — long
// sequential streams instead of 16-way 1-MB-strided gathers. Per-pixel online
// state (running max m, running sumexp s, gathered logit xt) lives in
// registers: 2 float4 groups per thread.
// Lane mapping within the strip (wave w = tid>>6, lane = tid&63, group g):
//   float-offset = w*512 + g*256 + lane*4   -> per-instr contiguous 1 KB/wave.
// ---------------------------------------------------------------------------
__global__ __launch_bounds__(256) void dwce_main(const float* __restrict__ pred,
                                                 const int* __restrict__ tgt,
                                                 float* __restrict__ partials) {
    __shared__ float s_bin[32];   // [0..15] sum(lp_t) per class, [16..31] count
    const int tid = threadIdx.x;
    if (tid < 32) s_bin[tid] = 0.0f;
    __syncthreads();

    const int b = blockIdx.x;
    const long long px0 = (long long)b * PXB;      // strip start (one image)
    const int n_img = (int)(px0 >> 18);
    const int hw0   = (int)(px0 & (HW - 1));
    const float* base = pred + (size_t)n_img * NCLS * HW + hw0;

    const int w    = tid >> 6;                     // wave id 0..3
    const int lane = tid & 63;
    int idx[GROUPS];                               // float offsets within strip
#pragma unroll
    for (int g = 0; g < GROUPS; ++g)
        idx[g] = w * (GROUPS * 256) + g * 256 + lane * 4;

    // target classes for this thread's 8 pixels (kept in VGPRs)
    int4 t[GROUPS];
#pragma unroll
    for (int g = 0; g < GROUPS; ++g)
        t[g] = *(const int4*)(tgt + px0 + idx[g]);

    float4 m[GROUPS], s[GROUPS], xt[GROUPS];
#pragma unroll
    for (int g = 0; g < GROUPS; ++g) {
        m[g]  = make_float4(-3.0e38f, -3.0e38f, -3.0e38f, -3.0e38f);
        s[g]  = make_float4(0.f, 0.f, 0.f, 0.f);
        xt[g] = make_float4(0.f, 0.f, 0.f, 0.f);
    }

#pragma unroll 2          // bound simultaneous channel-streams per wave
    for (int c = 0; c < NCLS; ++c) {
        const float* cb = base + (size_t)c * HW;
#pragma unroll
        for (int g = 0; g < GROUPS; ++g) {
            const float4 v = *(const float4*)(cb + idx[g]);
            // online logsumexp update (componentwise)
            float4 mn;
            mn.x = fmaxf(m[g].x, v.x);
            mn.y = fmaxf(m[g].y, v.y);
            mn.z = fmaxf(m[g].z, v.z);
            mn.w = fmaxf(m[g].w, v.w);
            s[g].x = s[g].x * __expf(m[g].x - mn.x) + __expf(v.x - mn.x);
            s[g].y = s[g].y * __expf(m[g].y - mn.y) + __expf(v.y - mn.y);
            s[g].z = s[g].z * __expf(m[g].z - mn.z) + __expf(v.z - mn.z);
            s[g].w = s[g].w * __expf(m[g].w - mn.w) + __expf(v.w - mn.w);
            m[g] = mn;
            // gather logit at target class (v_cndmask, no divergence)
            if (t[g].x == c) xt[g].x = v.x;
            if (t[g].y == c) xt[g].y = v.y;
            if (t[g].z == c) xt[g].z = v.z;
            if (t[g].w == c) xt[g].w = v.w;
        }
    }

    // per-pixel lp_t, accumulate into per-block (class-sum, class-count) bins
#pragma unroll
    for (int g = 0; g < GROUPS; ++g) {
        const float lp0 = xt[g].x - (m[g].x + __logf(s[g].x));
        const float lp1 = xt[g].y - (m[g].y + __logf(s[g].y));
        const float lp2 = xt[g].z - (m[g].z + __logf(s[g].z));
        const float lp3 = xt[g].w - (m[g].w + __logf(s[g].w));
        atomicAdd(&s_bin[t[g].x], lp0);
        atomicAdd(&s_bin[t[g].y], lp1);
        atomicAdd(&s_bin[t[g].z], lp2);
        atomicAdd(&s_bin[t[g].w], lp3);
        atomicAdd(&s_bin[16 + t[g].x], 1.0f);
        atomicAdd(&s_bin[16 + t[g].y], 1.0f);
        atomicAdd(&s_bin[16 + t[g].z], 1.0f);
        atomicAdd(&s_bin[16 + t[g].w], 1.0f);
    }

    __syncthreads();
    if (tid < 32)   // non-atomic per-block partials, c-major: partials[c][block]
        partials[(size_t)tid * NBLK + b] = s_bin[tid];
}

// ---------------------------------------------------------------------------
// Finalize: reduce 1024 block-partials per bin, build w_class from global
// counts, compute -mean_n(num/den). Single block, 256 threads.
// Image n owns blocks [n*128, (n+1)*128) -> contiguous 128 floats per (c,n).
// ---------------------------------------------------------------------------
__global__ __launch_bounds__(256) void dwce_final(const float* __restrict__ ws,
                                                  float* __restrict__ out) {
    __shared__ float tot[32][NIMG];   // [c(0..31)][n]
    __shared__ float wcl[NCLS];
    __shared__ float ratio[NIMG];
    const int tid = threadIdx.x;
    const int c = tid >> 3;           // 0..31
    const int n = tid & 7;            // 0..7

    const float4* p = (const float4*)(ws + (size_t)c * NBLK + n * 128);
    float4 a = make_float4(0.f, 0.f, 0.f, 0.f);
#pragma unroll 8
    for (int k = 0; k < 32; ++k) {
        float4 q = p[k];
        a.x += q.x; a.y += q.y; a.z += q.z; a.w += q.w;
    }
    tot[c][n] = (a.x + a.y) + (a.z + a.w);
    __syncthreads();

    if (tid < NCLS) {
        float g = 0.f;
#pragma unroll
        for (int i = 0; i < NIMG; ++i) g += tot[NCLS + tid][i];   // global count
        wcl[tid] = (g > 0.f) ? 1.0f / (g * (float)NCLS) : 0.0f;
    }
    __syncthreads();
    if (tid < NIMG) {
        float num = 0.f, den = 0.f;
#pragma unroll
        for (int c2 = 0; c2 < NCLS; ++c2) {
            num += tot[c2][tid] * wcl[c2];
            den += tot[NCLS + c2][tid] * wcl[c2];
        }
        ratio[tid] = num / den;
    }
    __syncthreads();
    if (tid == 0) {
        float r = 0.f;
#pragma unroll
        for (int i = 0; i < NIMG; ++i) r += ratio[i];
        out[0] = -r * (1.0f / (float)NIMG);
    }
}

extern "C" void kernel_launch(void* const* d_in, const int* in_sizes, int n_in,
                              void* d_out, int out_size, void* d_ws, size_t ws_size,
                              hipStream_t stream) {
    const float* pred = (const float*)d_in[0];
    const int*   tgt  = (const int*)d_in[1];
    // d_in[2] (weights) is ignored by the reference.
    float* out = (float*)d_out;
    float* ws  = (float*)d_ws;   // 32*NBLK floats = 128 KB, fully overwritten

    dwce_main<<<NBLK, 256, 0, stream>>>(pred, tgt, ws);
    dwce_final<<<1, 256, 0, stream>>>(ws, out);
}

// Round 4
// 206.758 us; speedup vs baseline: 1.0786x; 1.0786x over previous
//
#include <hip/hip_runtime.h>
#include <stdint.h>

// Problem constants (fixed by the reference): n=8, c=16, H=W=512.
#define NIMG 8
#define NCLS 16
#define HW   262144            // 512*512 = 2^18 pixels per image
#define PXB  1024              // pixels per block tile
#define NBLK 2048              // (NIMG*HW)/PXB ; 256 blocks per image

// Async global->LDS, 16B per lane, no destination VGPRs, no vmcnt batching.
// LDS dest semantics: wave-uniform base + lane*16 (m104/m108) — our layout
// is exactly that (strip base + wave*1KB + lane*16B).
__device__ __forceinline__ void g2lds16(const float* g, float* l) {
    __builtin_amdgcn_global_load_lds(
        (const __attribute__((address_space(1))) unsigned int*)g,
        (__attribute__((address_space(3))) unsigned int*)l,
        16, 0, 0);
}

// ---------------------------------------------------------------------------
// Main pass. Block b owns 1024 consecutive pixels of one image.
// Stage: 16 channels x 4KB strips -> 64KB LDS tile via global_load_lds
//        (16 outstanding 1KB loads per wave -> ~128KB in flight per CU).
// Compute: two LDS passes (max+gather, sum-exp), ds_read_b128 conflict-free.
// Accumulate per-block (class-sum, class-count) in LDS, write non-atomic
// per-block partials (c-major).
// ---------------------------------------------------------------------------
__global__ __launch_bounds__(256) void dwce_main(const float* __restrict__ pred,
                                                 const int* __restrict__ tgt,
                                                 float* __restrict__ partials) {
    __shared__ float tile[NCLS * PXB];   // 64 KB: [c][1024 px]
    __shared__ float s_bin[32];          // [0..15] sum(lp_t), [16..31] count
    const int tid = threadIdx.x;
    if (tid < 32) s_bin[tid] = 0.0f;

    const int b = blockIdx.x;
    const long long px0 = (long long)b * PXB;      // tile start (one image)
    const int n_img = (int)(px0 >> 18);
    const int hw0   = (int)(px0 & (HW - 1));
    const float* base = pred + (size_t)n_img * NCLS * HW + hw0;

    const int w    = tid >> 6;           // wave 0..3
    const int lane = tid & 63;
    const int woff = w * 256 + lane * 4; // float offset within a 1024px strip

    // Issue all 16 channel-strip loads back-to-back (deep vmcnt queue).
#pragma unroll
    for (int c = 0; c < NCLS; ++c)
        g2lds16(base + (size_t)c * HW + woff, &tile[c * PXB + woff]);

    // Targets for this thread's 4 pixels (regular load; drained by barrier).
    const int4 t4 = *(const int4*)(tgt + px0 + tid * 4);

    __syncthreads();   // compiler emits s_waitcnt vmcnt(0) before s_barrier

    const int p = tid * 4;               // this thread's 4 contiguous pixels

    // Pass 1: componentwise max over channels + gather logit at target class.
    float4 m  = make_float4(-3.0e38f, -3.0e38f, -3.0e38f, -3.0e38f);
    float4 xt = make_float4(0.f, 0.f, 0.f, 0.f);
#pragma unroll
    for (int c = 0; c < NCLS; ++c) {
        const float4 v = *(const float4*)&tile[c * PXB + p];  // ds_read_b128
        m.x = fmaxf(m.x, v.x);
        m.y = fmaxf(m.y, v.y);
        m.z = fmaxf(m.z, v.z);
        m.w = fmaxf(m.w, v.w);
        if (t4.x == c) xt.x = v.x;   // -> v_cndmask, no divergence
        if (t4.y == c) xt.y = v.y;
        if (t4.z == c) xt.z = v.z;
        if (t4.w == c) xt.w = v.w;
    }

    // Pass 2: sum of exp(v - m).
    float4 s = make_float4(0.f, 0.f, 0.f, 0.f);
#pragma unroll
    for (int c = 0; c < NCLS; ++c) {
        const float4 v = *(const float4*)&tile[c * PXB + p];
        s.x += __expf(v.x - m.x);
        s.y += __expf(v.y - m.y);
        s.z += __expf(v.z - m.z);
        s.w += __expf(v.w - m.w);
    }

    const float lp0 = xt.x - (m.x + __logf(s.x));
    const float lp1 = xt.y - (m.y + __logf(s.y));
    const float lp2 = xt.z - (m.z + __logf(s.z));
    const float lp3 = xt.w - (m.w + __logf(s.w));

    atomicAdd(&s_bin[t4.x], lp0);
    atomicAdd(&s_bin[t4.y], lp1);
    atomicAdd(&s_bin[t4.z], lp2);
    atomicAdd(&s_bin[t4.w], lp3);
    atomicAdd(&s_bin[16 + t4.x], 1.0f);
    atomicAdd(&s_bin[16 + t4.y], 1.0f);
    atomicAdd(&s_bin[16 + t4.z], 1.0f);
    atomicAdd(&s_bin[16 + t4.w], 1.0f);

    __syncthreads();
    if (tid < 32)   // non-atomic per-block partials, c-major: partials[c][block]
        partials[(size_t)tid * NBLK + b] = s_bin[tid];
}

// ---------------------------------------------------------------------------
// Finalize: reduce 2048 block-partials per bin, build w_class from global
// counts, compute -mean_n(num/den). Single block, 256 threads.
// Image n owns blocks [n*256, (n+1)*256) -> contiguous 256 floats per (c,n).
// ---------------------------------------------------------------------------
__global__ __launch_bounds__(256) void dwce_final(const float* __restrict__ ws,
                                                  float* __restrict__ out) {
    __shared__ float tot[32][NIMG];   // [c(0..31)][n]
    __shared__ float wcl[NCLS];
    __shared__ float ratio[NIMG];
    const int tid = threadIdx.x;
    const int c = tid >> 3;           // 0..31
    const int n = tid & 7;            // 0..7

    const float4* p = (const float4*)(ws + (size_t)c * NBLK + n * 256);
    float4 a = make_float4(0.f, 0.f, 0.f, 0.f);
#pragma unroll 8
    for (int k = 0; k < 64; ++k) {
        float4 q = p[k];
        a.x += q.x; a.y += q.y; a.z += q.z; a.w += q.w;
    }
    tot[c][n] = (a.x + a.y) + (a.z + a.w);
    __syncthreads();

    if (tid < NCLS) {
        float g = 0.f;
#pragma unroll
        for (int i = 0; i < NIMG; ++i) g += tot[NCLS + tid][i];   // global count
        wcl[tid] = (g > 0.f) ? 1.0f / (g * (float)NCLS) : 0.0f;
    }
    __syncthreads();
    if (tid < NIMG) {
        float num = 0.f, den = 0.f;
#pragma unroll
        for (int c2 = 0; c2 < NCLS; ++c2) {
            num += tot[c2][tid] * wcl[c2];
            den += tot[NCLS + c2][tid] * wcl[c2];
        }
        ratio[tid] = num / den;
    }
    __syncthreads();
    if (tid == 0) {
        float r = 0.f;
#pragma unroll
        for (int i = 0; i < NIMG; ++i) r += ratio[i];
        out[0] = -r * (1.0f / (float)NIMG);
    }
}

extern "C" void kernel_launch(void* const* d_in, const int* in_sizes, int n_in,
                              void* d_out, int out_size, void* d_ws, size_t ws_size,
                              hipStream_t stream) {
    const float* pred = (const float*)d_in[0];
    const int*   tgt  = (const int*)d_in[1];
    // d_in[2] (weights) is ignored by the reference.
    float* out = (float*)d_out;
    float* ws  = (float*)d_ws;   // 32*NBLK floats = 256 KB, fully overwritten

    dwce_main<<<NBLK, 256, 0, stream>>>(pred, tgt, ws);
    dwce_final<<<1, 256, 0, stream>>>(ws, out);
}